// Round 9
// baseline (1433.379 us; speedup 1.0000x reference)
//
#include <hip/hip_runtime.h>
#include <type_traits>

#define DEVINL __device__ __forceinline__

typedef short bf16x8 __attribute__((ext_vector_type(8)));
typedef float f32x4 __attribute__((ext_vector_type(4)));

DEVINL unsigned f2b(float f) {  // f32 -> bf16 bits (round to nearest even)
  unsigned u = __float_as_uint(f);
  u = (u + 0x7FFFu + ((u >> 16) & 1u)) >> 16;
  return u & 0xFFFFu;
}
DEVINL uint4 pack8(const float* v) {
  uint4 u;
  u.x = f2b(v[0]) | (f2b(v[1]) << 16);
  u.y = f2b(v[2]) | (f2b(v[3]) << 16);
  u.z = f2b(v[4]) | (f2b(v[5]) << 16);
  u.w = f2b(v[6]) | (f2b(v[7]) << 16);
  return u;
}

#if defined(__has_builtin)
#if __has_builtin(__builtin_amdgcn_global_load_lds)
#define HAVE_GLL 1
#endif
#endif
#ifndef HAVE_GLL
#define HAVE_GLL 0
#endif

// Stage 16B/lane global -> LDS. l is the wave-uniform chunk base; lane i's data
// lands at l + i*16B (lane-linear layout).
DEVINL void stage16(const unsigned short* g, unsigned short* l) {
#if HAVE_GLL
  __builtin_amdgcn_global_load_lds(
      (const __attribute__((address_space(1))) void*)g,
      (__attribute__((address_space(3))) void*)l, 16, 0, 0);
#else
  const int lane = threadIdx.x & 63;
  ((uint4*)l)[lane] = *(const uint4*)g;
#endif
}

// ---------------- reduction helpers ----------------
DEVINL float4 block_sum4(float4 v, float4* sh) {
  const int lane = threadIdx.x & 63, wid = threadIdx.x >> 6;
#pragma unroll
  for (int o = 32; o; o >>= 1) {
    v.x += __shfl_down(v.x, o);
    v.y += __shfl_down(v.y, o);
    v.z += __shfl_down(v.z, o);
    v.w += __shfl_down(v.w, o);
  }
  __syncthreads();
  if (lane == 0) sh[wid] = v;
  __syncthreads();
  float4 a = sh[0], b = sh[1], c = sh[2], d = sh[3], r;
  r.x = a.x + b.x + c.x + d.x;
  r.y = a.y + b.y + c.y + d.y;
  r.z = a.z + b.z + c.z + d.z;
  r.w = a.w + b.w + c.w + d.w;
  return r;
}
DEVINL float block_sum1(float v, float* sh) {
  const int lane = threadIdx.x & 63, wid = threadIdx.x >> 6;
#pragma unroll
  for (int o = 32; o; o >>= 1) v += __shfl_down(v, o);
  __syncthreads();
  if (lane == 0) sh[wid] = v;
  __syncthreads();
  return sh[0] + sh[1] + sh[2] + sh[3];
}

// ---- table projection: P[v,j] = scl*(V[v,:] @ W[:,j]), P[nvec,j] = scl*(bias @ W) ----
__global__ __launch_bounds__(256) void tabproj_kernel(
    const float* __restrict__ V, const float* __restrict__ bias,
    const float* __restrict__ W, float* __restrict__ P, int nvec, float scl) {
  __shared__ float4 sh4[4];
  const int j = blockIdx.x, tid = threadIdx.x;
  float acc[4] = {0.f, 0.f, 0.f, 0.f};
  for (int kk = tid; kk < 512; kk += 256) {
    const float w = W[(size_t)kk * 512 + j];
    for (int v = 0; v < nvec; ++v) acc[v] += V[(size_t)v * 512 + kk] * w;
    acc[3] += bias[kk] * w;
  }
  float4 packed = make_float4(acc[0], acc[1], acc[2], acc[3]);
  packed = block_sum4(packed, sh4);
  if (tid == 0) {
    const float vals[4] = {packed.x * scl, packed.y * scl, packed.z * scl, packed.w * scl};
    for (int v = 0; v < nvec; ++v) P[(size_t)v * 512 + j] = vals[v];
    P[(size_t)nvec * 512 + j] = vals[3];
  }
}

// ---- weight prep: src f32 [K][N] -> dst bf16 [N][K], scaled ----
__global__ __launch_bounds__(256) void transpose_bf_kernel(
    const float* __restrict__ src, unsigned short* __restrict__ dst, int K, int N,
    float scl) {
  __shared__ float tile[32][33];
  const int n0 = blockIdx.x * 32, k0 = blockIdx.y * 32;
  const int tx = threadIdx.x, ty = threadIdx.y;  // 32 x 8
#pragma unroll
  for (int r = 0; r < 4; ++r)
    tile[ty + 8 * r][tx] = src[(size_t)(k0 + ty + 8 * r) * N + n0 + tx];
  __syncthreads();
#pragma unroll
  for (int r = 0; r < 4; ++r)
    dst[(size_t)(n0 + ty + 8 * r) * K + k0 + tx] =
        (unsigned short)f2b(scl * tile[tx][ty + 8 * r]);
}

// ---- pack self-side K: KVQbf bf16 [4096][1536] cols 0..511 -> Kfr frag layout ----
// Kfr: [bh][kc=8][stile=64][lane=64][8]; nh=2, D=256.
__global__ __launch_bounds__(64) void pack_k_kernel(
    const unsigned short* __restrict__ KVQbf, unsigned short* __restrict__ Kfr) {
  const int row = blockIdx.x;  // b*1024 + s
  const int b = row >> 10, s = row & 1023;
  const int c = threadIdx.x;
  const int h = c >> 5;
  const int d0 = (c & 31) * 8;
  const uint4 u = *(const uint4*)(KVQbf + (size_t)row * 1536 + h * 256 + d0);
  const int bh = b * 2 + h;
  const int kc = d0 >> 5;
  const int lane = ((d0 & 31) >> 3) * 16 + (s & 15);
  *(uint4*)(Kfr + ((size_t)(bh * 8 + kc) * 64 + (s >> 4)) * 512 + lane * 8) = u;
}

// ---- V bf16 [4096][ld] (head cols at h*D) -> Vfr [bh][sc=32][dtile=D/16][lane][8] ----
__global__ __launch_bounds__(256) void vtrans_frag_kernel(
    const unsigned short* __restrict__ V, int ld, int nh, int D,
    unsigned short* __restrict__ Vfr) {
  __shared__ unsigned short tile[32][34];
  const int s0 = blockIdx.x * 32, d0 = blockIdx.y * 32;
  const int bh = blockIdx.z;
  const int b = bh / nh, h = bh % nh;
  const int tx = threadIdx.x, ty = threadIdx.y;  // 32 x 8
  const unsigned short* src = V + ((size_t)b * 1024 + s0) * ld + h * D + d0;
#pragma unroll
  for (int r = 0; r < 4; ++r)
    tile[ty + 8 * r][tx] = src[(size_t)(ty + 8 * r) * ld + tx];  // [s][d]
  __syncthreads();
  const int idx = ty * 32 + tx;
  if (idx < 128) {
    const int dj = idx & 31, sch = idx >> 5;
    uint4 u;
    unsigned short* up = (unsigned short*)&u;
#pragma unroll
    for (int jj = 0; jj < 8; ++jj) up[jj] = tile[sch * 8 + jj][dj];
    const int sc = s0 >> 5;
    const int dtile = (d0 + dj) >> 4;
    const int lane = sch * 16 + (dj & 15);
    *(uint4*)(Vfr + ((size_t)(bh * 32 + sc) * (D / 16) + dtile) * 512 + lane * 8) = u;
  }
}

// ---- cross-side encoder: rank-3 affine -> Kfr + Qbf (bh-packed) + V bf16 rows ----
// nh=2, D=256. Tables T*: rows 0..2 = vectors, row 3 (at +1536) = bias.
__global__ __launch_bounds__(192) void affine3_pack_kernel(
    const float* __restrict__ cx, const float* __restrict__ cy, int sel,
    const float* __restrict__ TK, const float* __restrict__ TV,
    const float* __restrict__ TQ, unsigned short* __restrict__ Kfr,
    unsigned short* __restrict__ Qbf, unsigned short* __restrict__ Vbf) {
  const int row = blockIdx.x;
  const int b = row >> 10, s = row & 1023;
  const float x = cx[row];
  const float* y = cy + (size_t)row * 8 + 2 * sel;
  const float y0 = y[0], y1 = y[1];
  const int t = threadIdx.x;
  if (t < 128) {
    const bool isQ = t >= 64;
    const int c = t & 63;
    const int h = c >> 5;
    const int d0 = (c & 31) * 8;
    const float* T = isQ ? TQ : TK;
    float v[8];
#pragma unroll
    for (int j = 0; j < 8; ++j) {
      const int col = h * 256 + d0 + j;
      v[j] = x * T[col] + y0 * T[512 + col] + y1 * T[1024 + col] + T[1536 + col];
    }
    const uint4 u = pack8(v);
    const int bh = b * 2 + h;
    if (isQ) {
      *(uint4*)(Qbf + ((size_t)bh * 1024 + s) * 256 + d0) = u;
    } else {
      const int kc = d0 >> 5;
      const int lane = ((d0 & 31) >> 3) * 16 + (s & 15);
      *(uint4*)(Kfr + ((size_t)(bh * 8 + kc) * 64 + (s >> 4)) * 512 + lane * 8) = u;
    }
  } else {
    const int c = t - 128;        // 64 chunks of 8 -> 512 cols
    const int d0 = c * 8;
    float v[8];
#pragma unroll
    for (int j = 0; j < 8; ++j) {
      const int col = d0 + j;
      v[j] = x * TV[col] + y0 * TV[512 + col] + y1 * TV[1024 + col] + TV[1536 + col];
    }
    *(uint4*)(Vbf + (size_t)row * 512 + d0) = pack8(v);
  }
}

// ---- decoder rank-1 producers (nh=4, D=128): T rows [0]=w, [1]=bias ----
__global__ __launch_bounds__(64) void rank1_pack_kernel(
    const float* __restrict__ x, const float* __restrict__ T,
    unsigned short* __restrict__ dst, int isQ) {
  const int row = blockIdx.x;
  const int b = row >> 10, s = row & 1023;
  const float xv = x[row];
  const int c = threadIdx.x;
  const int h = c >> 4;
  const int d0 = (c & 15) * 8;
  float v[8];
#pragma unroll
  for (int j = 0; j < 8; ++j) {
    const int col = h * 128 + d0 + j;
    v[j] = xv * T[col] + T[512 + col];
  }
  const uint4 u = pack8(v);
  const int bh = b * 4 + h;
  if (isQ) {
    *(uint4*)(dst + ((size_t)bh * 1024 + s) * 128 + d0) = u;
  } else {
    const int kc = d0 >> 5;
    const int lane = ((d0 & 31) >> 3) * 16 + (s & 15);
    *(uint4*)(dst + ((size_t)(bh * 4 + kc) * 64 + (s >> 4)) * 512 + lane * 8) = u;
  }
}

// ---- out[r,:] = cx[r]*W3[0,:] + y0*W3[1,:] + y1*W3[2,:] + bias (f32 + bf16) ----
__global__ __launch_bounds__(512) void affine3_kernel(
    const float* __restrict__ cx, const float* __restrict__ cy, int sel,
    const float* __restrict__ W3, const float* __restrict__ bias,
    float* __restrict__ out, unsigned short* __restrict__ outb) {
  const int r = blockIdx.x, j = threadIdx.x;
  const float* y = cy + (size_t)r * 8 + 2 * sel;
  const float v = cx[r] * W3[j] + y[0] * W3[512 + j] + y[1] * W3[1024 + j] + bias[j];
  if (out) out[(size_t)r * 512 + j] = v;
  if (outb) outb[(size_t)r * 512 + j] = (unsigned short)f2b(v);
}

// ---- out[r,:] = x[r]*w + b ----
__global__ __launch_bounds__(512) void rank1_kernel(
    const float* __restrict__ x, const float* __restrict__ w,
    const float* __restrict__ b, float* __restrict__ out,
    unsigned short* __restrict__ outb) {
  const int r = blockIdx.x, j = threadIdx.x;
  const float v = x[r] * w[j] + b[j];
  if (out) out[(size_t)r * 512 + j] = v;
  if (outb) outb[(size_t)r * 512 + j] = (unsigned short)f2b(v);
}

// ------- m97-style MFMA GEMM: C = [A0 | A1] @ Wt^T (+bias), async LDS staging -----
// BM=128, BK=32; BN=128 (4 waves x 64x64) or BN=64 (4 waves x 64x32).
// LDS layout per 16-row chunk is lane-linear (row = lane&15, kq = lane>>4) ->
// frag ds_read at chunkbase + lane*16B = conflict-free.
template <int BN, typename TOUT>
__global__ __launch_bounds__(256) void gemm2_kernel(
    const unsigned short* __restrict__ A0, int K0,
    const unsigned short* __restrict__ A1, int K1,
    const unsigned short* __restrict__ Wt, const float* __restrict__ bias,
    TOUT* __restrict__ C, int M, int N) {
  constexpr int BM = 128, BK = 32;
  constexpr int NT = BN / 32;  // B tiles per wave
  __shared__ unsigned short As[BM * BK];
  __shared__ unsigned short Bs[BN * BK];
  const int tid = threadIdx.x, lane = tid & 63, w = tid >> 6;
  const int l15 = lane & 15;
  const int bm = blockIdx.y * BM, bn = blockIdx.x * BN;
  const int wm = (w & 1) * 64, wn = (w >> 1) * (BN / 2);
  const int arow = lane & 15, acol = (lane >> 4) * 8;  // staging lane roles
  const int Ktot = K0 + K1;
  f32x4 acc[4][NT] = {};
  for (int k0 = 0; k0 < Ktot; k0 += BK) {
    const unsigned short* A;
    int kk, Ak;
    if (k0 < K0) { A = A0; kk = k0;      Ak = K0; }
    else         { A = A1; kk = k0 - K0; Ak = K1; }
    __syncthreads();  // previous iter's ds_reads done before overwrite
    // A: wave w stages rows 32w..32w+31 (2 chunks of 16)
#pragma unroll
    for (int c = 0; c < 2; ++c) {
      const int r0 = w * 32 + c * 16;
      stage16(A + (size_t)(bm + r0 + arow) * Ak + kk + acol, As + r0 * BK);
    }
    if constexpr (BN == 128) {
#pragma unroll
      for (int c = 0; c < 2; ++c) {
        const int r0 = w * 32 + c * 16;
        stage16(Wt + (size_t)(bn + r0 + arow) * Ktot + k0 + acol, Bs + r0 * BK);
      }
    } else {
      const int r0 = w * 16;
      stage16(Wt + (size_t)(bn + r0 + arow) * Ktot + k0 + acol, Bs + r0 * BK);
    }
    __syncthreads();  // drains vmcnt (incl. global_load_lds) + barrier
    bf16x8 af[4], bfr[NT];
#pragma unroll
    for (int mt = 0; mt < 4; ++mt)
      af[mt] = *(const bf16x8*)(As + (wm + mt * 16) * BK + lane * 8);
#pragma unroll
    for (int nt = 0; nt < NT; ++nt)
      bfr[nt] = *(const bf16x8*)(Bs + (wn + nt * 16) * BK + lane * 8);
#pragma unroll
    for (int mt = 0; mt < 4; ++mt)
#pragma unroll
      for (int nt = 0; nt < NT; ++nt)
        acc[mt][nt] =
            __builtin_amdgcn_mfma_f32_16x16x32_bf16(af[mt], bfr[nt], acc[mt][nt], 0, 0, 0);
  }
  const int lq = lane >> 4;
#pragma unroll
  for (int nt = 0; nt < NT; ++nt) {
    const int col = bn + wn + nt * 16 + l15;
    const float bv = bias ? bias[col] : 0.f;
#pragma unroll
    for (int mt = 0; mt < 4; ++mt) {
#pragma unroll
      for (int r = 0; r < 4; ++r) {
        const int row = bm + wm + mt * 16 + lq * 4 + r;
        if constexpr (std::is_same_v<TOUT, float>)
          C[(size_t)row * N + col] = acc[mt][nt][r] + bv;
        else
          C[(size_t)row * N + col] = (unsigned short)f2b(acc[mt][nt][r] + bv);
      }
    }
  }
}

// ---------------- MFMA flash attention, frag-packed inputs ----------------
// Block = 16 q rows of one (b,head); 4 waves own 256 keys each. Q pre-scaled.
// Q addressing: ldq==D -> bh-packed [bh*1024+s][D]; else row-packed
// [b*1024+s][ldq] at col qbase + head*D.
template <int D, int NKV>
__global__ __launch_bounds__(256, 2) void attn_mfma_kernel(
    const unsigned short* __restrict__ Qa, const unsigned short* __restrict__ Qb,
    int ldqa, int ldqb, int qbasea, int qbaseb,
    const unsigned short* __restrict__ KfrA, const unsigned short* __restrict__ KfrB,
    const unsigned short* __restrict__ VfrA, const unsigned short* __restrict__ VfrB,
    float post_scale, int nh, unsigned short* __restrict__ R) {
  constexpr int NQS = NKV;
  constexpr int QP = D + 8;
  constexpr int WP = 1024 + 8;
  constexpr int DT = D / 64;
  const int tid = threadIdx.x;
  const int lane = tid & 63, w = tid >> 6;
  const int l15 = lane & 15, lq = lane >> 4;
  const int nbh = 4 * nh;
  const int bh = blockIdx.x % nbh;  // XCD-local (b,h)
  const int qb16 = (blockIdx.x / nbh) * 16;
  const int b = bh / nh, head = bh % nh;
  const size_t rowb = (size_t)b * 1024;
  const int colo = head * D;

  __shared__ unsigned short qsh[NQS * 16 * QP];
  __shared__ unsigned short wsh[16 * WP];
  __shared__ float redA[4][16];
  __shared__ float redB[4][16];

  // ---- stage Q tiles (vectorized bf16 copies) ----
  for (int idx = tid; idx < NQS * 16 * (D / 8); idx += 256) {
    const int st = idx / (16 * (D / 8));
    const int rem = idx - st * 16 * (D / 8);
    const int r = rem / (D / 8), ch = rem - r * (D / 8);
    const unsigned short* Q = st ? Qb : Qa;
    const int ldq = st ? ldqb : ldqa;
    const int qb_ = st ? qbaseb : qbasea;
    const size_t rowi = (ldq == D) ? ((size_t)bh * 1024 + qb16 + r) : (rowb + qb16 + r);
    const int col = (ldq == D) ? 0 : (qb_ + colo);
    const uint4 u = *(const uint4*)(Q + rowi * (size_t)ldq + col + ch * 8);
    *(uint4*)(qsh + st * 16 * QP + r * QP + ch * 8) = u;
  }
  __syncthreads();

  f32x4 acc_o[DT] = {};

  for (int s = 0; s < NKV; ++s) {
    const unsigned short* Kp = (s ? KfrB : KfrA) + (size_t)bh * D * 1024;
    const unsigned short* Vp = (s ? VfrB : VfrA) + (size_t)bh * D * 1024;
    // ---- QK^T: batched kf loads, scores in C-layout regs ----
    f32x4 acc[NQS][16] = {};
#pragma unroll 1
    for (int kc = 0; kc < D / 32; ++kc) {
      bf16x8 kf[16];
#pragma unroll
      for (int st = 0; st < 16; ++st)
        kf[st] = *(const bf16x8*)(Kp + ((size_t)kc * 64 + w * 16 + st) * 512 + lane * 8);
      const bf16x8 qa = *(const bf16x8*)(qsh + l15 * QP + kc * 32 + lq * 8);
#pragma unroll
      for (int st = 0; st < 16; ++st)
        acc[0][st] = __builtin_amdgcn_mfma_f32_16x16x32_bf16(qa, kf[st], acc[0][st], 0, 0, 0);
      if constexpr (NKV == 2) {
        const bf16x8 qb2 = *(const bf16x8*)(qsh + 16 * QP + l15 * QP + kc * 32 + lq * 8);
#pragma unroll
        for (int st = 0; st < 16; ++st)
          acc[1][st] =
              __builtin_amdgcn_mfma_f32_16x16x32_bf16(qb2, kf[st], acc[1][st], 0, 0, 0);
      }
    }
    // ---- row max ----
    float pmA[4], pmB[4];
#pragma unroll
    for (int r = 0; r < 4; ++r) { pmA[r] = -3e38f; pmB[r] = -3e38f; }
#pragma unroll
    for (int st = 0; st < 16; ++st)
#pragma unroll
      for (int r = 0; r < 4; ++r) {
        pmA[r] = fmaxf(pmA[r], acc[0][st][r]);
        if constexpr (NKV == 2) pmB[r] = fmaxf(pmB[r], acc[1][st][r]);
      }
#pragma unroll
    for (int o = 1; o < 16; o <<= 1)
#pragma unroll
      for (int r = 0; r < 4; ++r) {
        pmA[r] = fmaxf(pmA[r], __shfl_xor(pmA[r], o));
        if constexpr (NKV == 2) pmB[r] = fmaxf(pmB[r], __shfl_xor(pmB[r], o));
      }
    __syncthreads();
    if (l15 == 0) {
#pragma unroll
      for (int r = 0; r < 4; ++r) {
        redA[w][lq * 4 + r] = pmA[r];
        if constexpr (NKV == 2) redB[w][lq * 4 + r] = pmB[r];
      }
    }
    __syncthreads();
    float mA[4], mB[4];
#pragma unroll
    for (int r = 0; r < 4; ++r) {
      mA[r] = fmaxf(fmaxf(redA[0][lq * 4 + r], redA[1][lq * 4 + r]),
                    fmaxf(redA[2][lq * 4 + r], redA[3][lq * 4 + r]));
      if constexpr (NKV == 2)
        mB[r] = fmaxf(fmaxf(redB[0][lq * 4 + r], redB[1][lq * 4 + r]),
                      fmaxf(redB[2][lq * 4 + r], redB[3][lq * 4 + r]));
    }
    // ---- exp + row sum ----
    float psA[4] = {0.f, 0.f, 0.f, 0.f}, psB[4] = {0.f, 0.f, 0.f, 0.f};
#pragma unroll
    for (int st = 0; st < 16; ++st)
#pragma unroll
      for (int r = 0; r < 4; ++r) {
        acc[0][st][r] = __expf(acc[0][st][r] - mA[r]);
        psA[r] += acc[0][st][r];
        if constexpr (NKV == 2) {
          acc[1][st][r] = __expf(acc[1][st][r] - mB[r]);
          psB[r] += acc[1][st][r];
        }
      }
#pragma unroll
    for (int o = 1; o < 16; o <<= 1)
#pragma unroll
      for (int r = 0; r < 4; ++r) {
        psA[r] += __shfl_xor(psA[r], o);
        if constexpr (NKV == 2) psB[r] += __shfl_xor(psB[r], o);
      }
    __syncthreads();
    if (l15 == 0) {
#pragma unroll
      for (int r = 0; r < 4; ++r) {
        redA[w][lq * 4 + r] = psA[r];
        if constexpr (NKV == 2) redB[w][lq * 4 + r] = psB[r];
      }
    }
    __syncthreads();
    float invA[4], invB[4];
#pragma unroll
    for (int r = 0; r < 4; ++r) {
      invA[r] = 1.f / (redA[0][lq * 4 + r] + redA[1][lq * 4 + r] +
                       redA[2][lq * 4 + r] + redA[3][lq * 4 + r]);
      if constexpr (NKV == 2)
        invB[r] = 1.f / (redB[0][lq * 4 + r] + redB[1][lq * 4 + r] +
                         redB[2][lq * 4 + r] + redB[3][lq * 4 + r]);
    }
    // ---- combined weight strip (bf16, A-operand layout) ----
#pragma unroll
    for (int st = 0; st < 16; ++st)
#pragma unroll
      for (int r = 0; r < 4; ++r) {
        float wv = acc[0][st][r] * invA[r];
        if constexpr (NKV == 2) wv += acc[1][st][r] * invB[r];
        wsh[(lq * 4 + r) * WP + w * 256 + st * 16 + l15] = (unsigned short)f2b(wv);
      }
    __syncthreads();
    // ---- PV: out[q][d] += W[q][s] V[s][d]; batch 2 sc-chunks of loads ----
#pragma unroll 1
    for (int sc = 0; sc < 32; sc += 2) {
      bf16x8 pa[2], vb[2][DT];
#pragma unroll
      for (int u = 0; u < 2; ++u) {
        pa[u] = *(const bf16x8*)(wsh + l15 * WP + (sc + u) * 32 + lq * 8);
#pragma unroll
        for (int dt = 0; dt < DT; ++dt)
          vb[u][dt] = *(const bf16x8*)(
              Vp + ((size_t)(sc + u) * (D / 16) + w * DT + dt) * 512 + lane * 8);
      }
#pragma unroll
      for (int u = 0; u < 2; ++u)
#pragma unroll
        for (int dt = 0; dt < DT; ++dt)
          acc_o[dt] =
              __builtin_amdgcn_mfma_f32_16x16x32_bf16(pa[u], vb[u][dt], acc_o[dt], 0, 0, 0);
    }
  }
  // ---- epilogue: C layout row=lq*4+r -> q, col=l15 -> d ----
#pragma unroll
  for (int dt = 0; dt < DT; ++dt)
#pragma unroll
    for (int r = 0; r < 4; ++r) {
      const int q = lq * 4 + r;
      const int d = w * (DT * 16) + dt * 16 + l15;
      R[(rowb + qb16 + q) * 512 + colo + d] = (unsigned short)f2b(acc_o[dt][r] * post_scale);
    }
}

// ------------- out = LayerNorm(G + res) * g + b  (f32 out + optional bf16 out) ----
__global__ __launch_bounds__(256) void ln_kernel(
    const float* __restrict__ G, const float* __restrict__ res,
    const float* __restrict__ g, const float* __restrict__ b,
    float* __restrict__ out, unsigned short* __restrict__ outb) {
  __shared__ float sh[4];
  const int row = blockIdx.x, tid = threadIdx.x;
  const size_t off = (size_t)row * 512;
  const float x0 = G[off + tid] + res[off + tid];
  const float x1 = G[off + tid + 256] + res[off + tid + 256];
  const float mean = block_sum1(x0 + x1, sh) * (1.0f / 512.0f);
  const float d0 = x0 - mean, d1 = x1 - mean;
  const float var = block_sum1(d0 * d0 + d1 * d1, sh) * (1.0f / 512.0f);
  const float inv = rsqrtf(var + 1e-5f);
  const float y0 = d0 * inv * g[tid] + b[tid];
  const float y1 = d1 * inv * g[tid + 256] + b[tid + 256];
  out[off + tid] = y0;
  out[off + tid + 256] = y1;
  if (outb) {
    outb[off + tid] = (unsigned short)f2b(y0);
    outb[off + tid + 256] = (unsigned short)f2b(y1);
  }
}

extern "C" void kernel_launch(void* const* d_in, const int* in_sizes, int n_in,
                              void* d_out, int out_size, void* d_ws, size_t ws_size,
                              hipStream_t stream) {
  typedef unsigned short ushort_t;
  const float* cx   = (const float*)d_in[0];
  const float* cy   = (const float*)d_in[1];
  const float* txp  = (const float*)d_in[2];
  const float* in_W = (const float*)d_in[3];
  const float* in_b = (const float*)d_in[4];
  const float* cx_W = (const float*)d_in[5];
  const float* cx_b = (const float*)d_in[6];
  const float* tx_W = (const float*)d_in[7];
  const float* tx_b = (const float*)d_in[8];
  const float* sWk  = (const float*)d_in[9];
  const float* sWv  = (const float*)d_in[10];
  const float* sWq  = (const float*)d_in[11];
  const float* sWf  = (const float*)d_in[12];
  const float* sbf  = (const float*)d_in[13];
  const float* sg   = (const float*)d_in[14];
  const float* sb   = (const float*)d_in[15];
  const float* aWk  = (const float*)d_in[16];
  const float* aWv  = (const float*)d_in[17];
  const float* aWq  = (const float*)d_in[18];
  const float* aWf  = (const float*)d_in[19];
  const float* abf  = (const float*)d_in[20];
  const float* ag   = (const float*)d_in[21];
  const float* ab   = (const float*)d_in[22];

  const float SSC = 0.0625f;               // 1/sqrt(256)
  const float CSC = 0.08838834764831845f;  // 1/sqrt(128)

  const size_t MB = 1024 * 1024;
  char* ws = (char*)d_ws;
  float*    E     = (float*)(ws + 0 * MB);        // 8 MB
  ushort_t* Ebf   = (ushort_t*)(ws + 8 * MB);     // 4 MB
  float*    QA    = (float*)(ws + 12 * MB);       // 8 MB
  ushort_t* QAbf  = (ushort_t*)(ws + 20 * MB);    // 4 MB
  ushort_t* Rbbf  = (ushort_t*)(ws + 24 * MB);    // 4 MB
  ushort_t* KVQbf = (ushort_t*)(ws + 28 * MB);    // 12 MB [4096][1536] bf16 K|V|Q
  float*    G     = (float*)(ws + 40 * MB);       // 8 MB
  ushort_t* KfrA  = (ushort_t*)(ws + 48 * MB);    // 4 MB
  ushort_t* VfrA  = (ushort_t*)(ws + 52 * MB);    // 4 MB
  ushort_t* KfrB  = (ushort_t*)(ws + 56 * MB);    // 4 MB
  ushort_t* VfrB  = (ushort_t*)(ws + 60 * MB);    // 4 MB
  ushort_t* QbfB  = (ushort_t*)(ws + 64 * MB);    // 4 MB (cross/decoder bh-packed Q)
  ushort_t* Vbf   = (ushort_t*)(ws + 68 * MB);    // 4 MB (cross/decoder V rows bf16)
  ushort_t* Qrow  = (ushort_t*)(ws + 72 * MB);    // 4 MB (decoder i=1 Q rows bf16)
  ushort_t* Wkvqt[2] = {(ushort_t*)(ws + 76 * MB), (ushort_t*)(ws + 78 * MB)};
  ushort_t* Wft[2]   = {(ushort_t*)(ws + 80 * MB), (ushort_t*)(ws + 81 * MB)};
  ushort_t* aWvt[2]  = {(ushort_t*)(ws + 82 * MB), (ushort_t*)(ws + 83 * MB)};
  ushort_t* aWqt1    = (ushort_t*)(ws + 84 * MB);
  ushort_t* aWft[2]  = {(ushort_t*)(ws + 85 * MB), (ushort_t*)(ws + 86 * MB)};
  float*    Ttab     = (float*)(ws + 88 * MB);

  float* T_sc[2][3];
  for (int i = 0; i < 2; ++i)
    for (int w = 0; w < 3; ++w) T_sc[i][w] = Ttab + (size_t)(i * 3 + w) * 2048;
  float* T_cak[2] = {Ttab + 12288, Ttab + 12288 + 1024};
  float* T_caq0 = Ttab + 14336;

  const dim3 tb(32, 8);
  const dim3 tg512(16, 16), tg1024(16, 32);

  // ---- prep: weight transposes + projection tables (Q weights pre-scaled) ----
  for (int i = 0; i < 2; ++i) {
    transpose_bf_kernel<<<tg512, tb, 0, stream>>>(sWk + (size_t)i * 262144, Wkvqt[i], 512, 512, 1.f);
    transpose_bf_kernel<<<tg512, tb, 0, stream>>>(sWv + (size_t)i * 262144, Wkvqt[i] + 512 * 512, 512, 512, 1.f);
    transpose_bf_kernel<<<tg512, tb, 0, stream>>>(sWq + (size_t)i * 262144, Wkvqt[i] + 1024 * 512, 512, 512, SSC);
    transpose_bf_kernel<<<tg1024, tb, 0, stream>>>(sWf + (size_t)i * 524288, Wft[i], 1024, 512, 1.f);
    transpose_bf_kernel<<<tg512, tb, 0, stream>>>(aWv + (size_t)i * 262144, aWvt[i], 512, 512, 1.f);
    transpose_bf_kernel<<<tg1024, tb, 0, stream>>>(aWf + (size_t)i * 524288, aWft[i], 1024, 512, 1.f);
    tabproj_kernel<<<512, 256, 0, stream>>>(in_W, in_b, sWk + (size_t)i * 262144, T_sc[i][0], 3, 1.f);
    tabproj_kernel<<<512, 256, 0, stream>>>(in_W, in_b, sWv + (size_t)i * 262144, T_sc[i][1], 3, 1.f);
    tabproj_kernel<<<512, 256, 0, stream>>>(in_W, in_b, sWq + (size_t)i * 262144, T_sc[i][2], 3, SSC);
    tabproj_kernel<<<512, 256, 0, stream>>>(cx_W, cx_b, aWk + (size_t)i * 262144, T_cak[i], 1, 1.f);
  }
  transpose_bf_kernel<<<tg512, tb, 0, stream>>>(aWq + 262144, aWqt1, 512, 512, CSC);
  tabproj_kernel<<<512, 256, 0, stream>>>(tx_W, tx_b, aWq, T_caq0, 1, CSC);

  // ---- initial activations ----
  affine3_kernel<<<4096, 512, 0, stream>>>(cx, cy, 0, in_W, in_b, E, Ebf);
  rank1_kernel<<<4096, 512, 0, stream>>>(txp, tx_W, tx_b, QA, QAbf);

  // ---- 8 self/cross encoder layers ----
  for (int p = 0; p < 4; ++p) {
    for (int i = 0; i < 2; ++i) {
      gemm2_kernel<128, ushort_t><<<dim3(12, 32), 256, 0, stream>>>(
          Ebf, 512, nullptr, 0, Wkvqt[i], nullptr, KVQbf, 4096, 1536);
      pack_k_kernel<<<4096, 64, 0, stream>>>(KVQbf, KfrA);
      vtrans_frag_kernel<<<dim3(32, 8, 8), tb, 0, stream>>>(KVQbf + 512, 1536, 2, 256, VfrA);
      if (p > 0) {
        affine3_pack_kernel<<<4096, 192, 0, stream>>>(cx, cy, p, T_sc[i][0], T_sc[i][1],
                                                      T_sc[i][2], KfrB, QbfB, Vbf);
        vtrans_frag_kernel<<<dim3(32, 8, 8), tb, 0, stream>>>(Vbf, 512, 2, 256, VfrB);
        attn_mfma_kernel<256, 2><<<512, 256, 0, stream>>>(
            KVQbf, QbfB, 1536, 256, 1024, 0, KfrA, KfrB, VfrA, VfrB, 1.0f, 2, Rbbf);
      } else {
        // x2 is x: 4 identical sdpa terms -> 4 * sdpa(sQ,sK,sV)
        attn_mfma_kernel<256, 1><<<512, 256, 0, stream>>>(
            KVQbf, KVQbf, 1536, 1536, 1024, 1024, KfrA, KfrA, VfrA, VfrA, 4.0f, 2, Rbbf);
      }
      gemm2_kernel<64, float><<<dim3(8, 32), 256, 0, stream>>>(
          Ebf, 512, Rbbf, 512, Wft[i], sbf + (size_t)i * 512, G, 4096, 512);
      ln_kernel<<<4096, 256, 0, stream>>>(G, E, sg + (size_t)i * 512, sb + (size_t)i * 512,
                                          E, Ebf);
    }
  }

  // ---- 2 cross-attention decoder layers (nh=4, D=128) ----
  for (int i = 0; i < 2; ++i) {
    rank1_pack_kernel<<<4096, 64, 0, stream>>>(cx, T_cak[i], KfrA, 0);
    gemm2_kernel<64, ushort_t><<<dim3(8, 32), 256, 0, stream>>>(
        Ebf, 512, nullptr, 0, aWvt[i], nullptr, Vbf, 4096, 512);
    vtrans_frag_kernel<<<dim3(32, 4, 16), tb, 0, stream>>>(Vbf, 512, 4, 128, VfrA);
    if (i == 0) {
      rank1_pack_kernel<<<4096, 64, 0, stream>>>(txp, T_caq0, QbfB, 1);
      attn_mfma_kernel<128, 1><<<1024, 256, 0, stream>>>(
          QbfB, QbfB, 128, 128, 0, 0, KfrA, KfrA, VfrA, VfrA, 1.0f, 4, Rbbf);
    } else {
      gemm2_kernel<64, ushort_t><<<dim3(8, 32), 256, 0, stream>>>(
          QAbf, 512, nullptr, 0, aWqt1, nullptr, Qrow, 4096, 512);
      attn_mfma_kernel<128, 1><<<1024, 256, 0, stream>>>(
          Qrow, Qrow, 512, 512, 0, 0, KfrA, KfrA, VfrA, VfrA, 1.0f, 4, Rbbf);
    }
    gemm2_kernel<64, float><<<dim3(8, 32), 256, 0, stream>>>(
        QAbf, 512, Rbbf, 512, aWft[i], abf + (size_t)i * 512, G, 4096, 512);
    ln_kernel<<<4096, 256, 0, stream>>>(G, QA, ag + (size_t)i * 512, ab + (size_t)i * 512,
                                        (i == 1) ? (float*)d_out : QA,
                                        (i == 1) ? nullptr : QAbf);
  }
  (void)in_sizes; (void)n_in; (void)out_size; (void)ws_size;
}